// Round 1
// baseline (631.760 us; speedup 1.0000x reference)
//
#include <hip/hip_runtime.h>
#include <math.h>

#define D 64

// ---------------------------------------------------------------------------
// Detect whether edge_index buffer is int64 or int32.
// Values are in [0, 1e5) >= 0, so if int64, every odd 32-bit word (high half)
// of the first 2048 elements is 0. If int32, those words are random indices.
__global__ void detect_i64_kernel(const unsigned int* __restrict__ ei,
                                  int* __restrict__ flag) {
    __shared__ unsigned int red[256];
    unsigned int v = 0;
    for (int i = threadIdx.x; i < 2048; i += 256)
        v |= ei[2 * i + 1];
    red[threadIdx.x] = v;
    __syncthreads();
    if (threadIdx.x == 0) {
        unsigned int o = 0;
        for (int i = 0; i < 256; ++i) o |= red[i];
        flag[0] = (o == 0) ? 1 : 0;   // 1 => int64 layout
    }
}

// Convert edge_index ([2, E], either int32 or int64) into packed int32 arrays.
__global__ void convert_edges_kernel(const void* __restrict__ ei,
                                     const int* __restrict__ flag,
                                     int* __restrict__ src32,
                                     int* __restrict__ dst32,
                                     int n_edges) {
    int e = blockIdx.x * blockDim.x + threadIdx.x;
    if (e >= n_edges) return;
    if (flag[0]) {
        const long long* p = (const long long*)ei;
        src32[e] = (int)p[e];
        dst32[e] = (int)p[n_edges + e];
    } else {
        const int* p = (const int*)ei;
        src32[e] = p[e];
        dst32[e] = p[n_edges + e];
    }
}

// ---------------------------------------------------------------------------
// agg[dst] += x[src] ; one 64-lane wave per edge, lane = feature index.
__global__ void scatter_add_kernel(const float* __restrict__ x,
                                   const int* __restrict__ src,
                                   const int* __restrict__ dst,
                                   float* __restrict__ agg,
                                   int n_edges) {
    int lane = threadIdx.x & 63;
    int wave = (blockIdx.x * blockDim.x + threadIdx.x) >> 6;
    int nwaves = (gridDim.x * blockDim.x) >> 6;
    for (int e = wave; e < n_edges; e += nwaves) {
        int s = src[e];
        int t = dst[e];
        atomicAdd(&agg[t * D + lane], x[s * D + lane]);
    }
}

// ---------------------------------------------------------------------------
// out[i] = act( agg[i] @ Wrel^T + brel + xin[i] @ Wroot^T )
// Weights staged transposed in LDS with +1 padding (stride 65) => conflict-free
// ds_read for lane=j at sW[k*65+j]. 4 nodes/block (1 wave each), grid-stride.
// NOTE: writing out == agg in-place is safe: each tile stages its rows into
// LDS before overwriting, and tiles partition the node set.
__global__ __launch_bounds__(256) void transform_kernel(
        const float* __restrict__ agg, const float* __restrict__ xin,
        const float* __restrict__ Wrel, const float* __restrict__ brel,
        const float* __restrict__ Wroot, float* __restrict__ out,
        int n_nodes, int do_tanh) {
    __shared__ float sWr[64 * 65];
    __shared__ float sWt[64 * 65];
    __shared__ float sA[4][64];
    __shared__ float sX[4][64];

    int tid = threadIdx.x;
    // stage transposed weights: sW[k*65 + j] = W[j*64 + k]
    for (int idx = tid; idx < 4096; idx += 256) {
        int j = idx >> 6, k = idx & 63;
        sWr[k * 65 + j] = Wrel[idx];
        sWt[k * 65 + j] = Wroot[idx];
    }
    __syncthreads();

    int lane = tid & 63;
    int w = tid >> 6;
    float bias = brel[lane];
    int ntiles = (n_nodes + 3) >> 2;

    for (int tile = blockIdx.x; tile < ntiles; tile += gridDim.x) {
        int node = tile * 4 + w;
        if (node < n_nodes) {
            sA[w][lane] = agg[node * D + lane];
            sX[w][lane] = xin[node * D + lane];
        }
        __syncthreads();
        if (node < n_nodes) {
            float acc = bias;
            #pragma unroll
            for (int k = 0; k < 64; ++k) {
                acc = fmaf(sA[w][k], sWr[k * 65 + lane], acc);
                acc = fmaf(sX[w][k], sWt[k * 65 + lane], acc);
            }
            out[node * D + lane] = do_tanh ? tanhf(acc) : acc;
        }
        __syncthreads();
    }
}

// ---------------------------------------------------------------------------
// out[i] = dot(h[i], Wout) + bout ; wave per node, shuffle reduce.
__global__ void out_kernel(const float* __restrict__ h,
                           const float* __restrict__ Wout,
                           const float* __restrict__ bout,
                           float* __restrict__ out, int n_nodes) {
    int lane = threadIdx.x & 63;
    int node = (blockIdx.x * blockDim.x + threadIdx.x) >> 6;
    if (node >= n_nodes) return;
    float v = h[node * D + lane] * Wout[lane];
    #pragma unroll
    for (int off = 32; off > 0; off >>= 1)
        v += __shfl_down(v, off);
    if (lane == 0) out[node] = v + bout[0];
}

// ---------------------------------------------------------------------------
extern "C" void kernel_launch(void* const* d_in, const int* in_sizes, int n_in,
                              void* d_out, int out_size, void* d_ws, size_t ws_size,
                              hipStream_t stream) {
    const float* x      = (const float*)d_in[0];
    const void*  ei     = d_in[1];
    const float* Wrel0  = (const float*)d_in[2];
    const float* brel0  = (const float*)d_in[3];
    const float* Wroot0 = (const float*)d_in[4];
    const float* Wrel1  = (const float*)d_in[5];
    const float* brel1  = (const float*)d_in[6];
    const float* Wroot1 = (const float*)d_in[7];
    const float* Wout   = (const float*)d_in[8];
    const float* bout   = (const float*)d_in[9];
    float* out = (float*)d_out;

    const int n_nodes = in_sizes[0] / D;
    const int n_edges = in_sizes[1] / 2;

    // workspace layout
    float* bufA  = (float*)d_ws;                 // [n_nodes * 64] agg / h2
    float* bufB  = bufA + (size_t)n_nodes * D;   // [n_nodes * 64] h
    int*   src32 = (int*)(bufB + (size_t)n_nodes * D);
    int*   dst32 = src32 + n_edges;
    int*   flag  = dst32 + n_edges;

    // edge preprocessing (dtype-robust)
    detect_i64_kernel<<<1, 256, 0, stream>>>((const unsigned int*)ei, flag);
    convert_edges_kernel<<<(n_edges + 255) / 256, 256, 0, stream>>>(
        ei, flag, src32, dst32, n_edges);

    const size_t feat_bytes = (size_t)n_nodes * D * sizeof(float);

    // ---- layer 0 ----
    hipMemsetAsync(bufA, 0, feat_bytes, stream);
    scatter_add_kernel<<<4096, 256, 0, stream>>>(x, src32, dst32, bufA, n_edges);
    transform_kernel<<<2048, 256, 0, stream>>>(bufA, x, Wrel0, brel0, Wroot0,
                                               bufB, n_nodes, 1);
    // ---- layer 1 ----
    hipMemsetAsync(bufA, 0, feat_bytes, stream);
    scatter_add_kernel<<<4096, 256, 0, stream>>>(bufB, src32, dst32, bufA, n_edges);
    transform_kernel<<<2048, 256, 0, stream>>>(bufA, bufB, Wrel1, brel1, Wroot1,
                                               bufA, n_nodes, 1);
    // ---- output head ----
    out_kernel<<<(n_nodes + 3) / 4, 256, 0, stream>>>(bufA, Wout, bout, out, n_nodes);
}

// Round 2
// 614.088 us; speedup vs baseline: 1.0288x; 1.0288x over previous
//
#include <hip/hip_runtime.h>
#include <math.h>

#define D 64

// ---------------------------------------------------------------------------
// Detect whether edge_index buffer is int64 or int32 (values < 2^31 => if
// int64, odd 32-bit words are all zero).
__global__ void detect_i64_kernel(const unsigned int* __restrict__ ei,
                                  int* __restrict__ flag) {
    __shared__ unsigned int red[256];
    unsigned int v = 0;
    for (int i = threadIdx.x; i < 2048; i += 256)
        v |= ei[2 * i + 1];
    red[threadIdx.x] = v;
    __syncthreads();
    if (threadIdx.x == 0) {
        unsigned int o = 0;
        for (int i = 0; i < 256; ++i) o |= red[i];
        flag[0] = (o == 0) ? 1 : 0;   // 1 => int64 layout
    }
}

__device__ __forceinline__ int load_idx(const void* ei, int flag, long long pos) {
    return flag ? (int)((const long long*)ei)[pos] : ((const int*)ei)[pos];
}

// ---------------------------------------------------------------------------
// Histogram of in-degrees.
__global__ void hist_kernel(const void* __restrict__ ei,
                            const int* __restrict__ flag,
                            int* __restrict__ deg, int n_edges) {
    int e = blockIdx.x * blockDim.x + threadIdx.x;
    if (e >= n_edges) return;
    int dst = load_idx(ei, flag[0], (long long)n_edges + e);
    atomicAdd(&deg[dst], 1);
}

// Single-block exclusive scan of deg[0..n) -> rowptr[0..n], rowptr[n]=total.
// Also copies rowptr into cursor for the fill pass.
__global__ __launch_bounds__(1024) void scan_kernel(const int* __restrict__ deg,
                                                    int* __restrict__ rowptr,
                                                    int* __restrict__ cursor,
                                                    int n) {
    __shared__ int part[1024];
    int t = threadIdx.x;
    int chunk = (n + 1023) / 1024;
    int b = t * chunk;
    int e = min(b + chunk, n);
    int s = 0;
    for (int i = b; i < e; ++i) s += deg[i];
    part[t] = s;
    __syncthreads();
    for (int off = 1; off < 1024; off <<= 1) {
        int v = (t >= off) ? part[t - off] : 0;
        __syncthreads();
        part[t] += v;
        __syncthreads();
    }
    int run = (t == 0) ? 0 : part[t - 1];
    for (int i = b; i < e; ++i) {
        rowptr[i] = run;
        cursor[i] = run;
        run += deg[i];
    }
    if (e == n) rowptr[n] = run;
}

// Fill CSR column array: col[pos] = src, sorted by dst.
__global__ void fill_kernel(const void* __restrict__ ei,
                            const int* __restrict__ flag,
                            int* __restrict__ cursor,
                            int* __restrict__ col, int n_edges) {
    int e = blockIdx.x * blockDim.x + threadIdx.x;
    if (e >= n_edges) return;
    int f = flag[0];
    int src = load_idx(ei, f, e);
    int dst = load_idx(ei, f, (long long)n_edges + e);
    int pos = atomicAdd(&cursor[dst], 1);
    col[pos] = src;
}

// ---------------------------------------------------------------------------
// Fused GraphConv layer: per node i (one wave each, lane = feature):
//   agg = sum_{e in [rowptr[i],rowptr[i+1])} xin[col[e]]
//   h   = tanh( agg @ Wrel^T + brel + xin[i] @ Wroot^T )
// If OUT_HEAD: out[i] = dot(h, Wout) + bout   (h never hits memory)
// else:        out[i*64 + lane] = h[lane]
template <bool OUT_HEAD>
__global__ __launch_bounds__(256) void layer_kernel(
        const float* __restrict__ xin,
        const int* __restrict__ rowptr, const int* __restrict__ col,
        const float* __restrict__ Wrel, const float* __restrict__ brel,
        const float* __restrict__ Wroot,
        const float* __restrict__ Wout, const float* __restrict__ bout,
        float* __restrict__ out, int n_nodes) {
    __shared__ float sWr[64 * 65];
    __shared__ float sWt[64 * 65];
    __shared__ float sA[4][64];
    __shared__ float sX[4][64];

    int tid = threadIdx.x;
    // stage transposed weights: sW[k*65 + j] = W[j*64 + k]
    for (int idx = tid; idx < 4096; idx += 256) {
        int j = idx >> 6, k = idx & 63;
        sWr[k * 65 + j] = Wrel[idx];
        sWt[k * 65 + j] = Wroot[idx];
    }
    __syncthreads();

    int lane = tid & 63;
    int w = tid >> 6;
    float bias = brel[lane];
    float wout = OUT_HEAD ? Wout[lane] : 0.f;
    int ntiles = (n_nodes + 3) >> 2;

    for (int tile = blockIdx.x; tile < ntiles; tile += gridDim.x) {
        int node = tile * 4 + w;
        if (node < n_nodes) {
            int beg = rowptr[node];
            int end = rowptr[node + 1];
            // gather-sum with 4 independent accumulators (4 loads in flight)
            float a0 = 0.f, a1 = 0.f, a2 = 0.f, a3 = 0.f;
            int e = beg;
            for (; e + 3 < end; e += 4) {
                int s0 = col[e], s1 = col[e + 1], s2 = col[e + 2], s3 = col[e + 3];
                a0 += xin[s0 * D + lane];
                a1 += xin[s1 * D + lane];
                a2 += xin[s2 * D + lane];
                a3 += xin[s3 * D + lane];
            }
            for (; e < end; ++e) a0 += xin[col[e] * D + lane];
            sA[w][lane] = (a0 + a1) + (a2 + a3);
            sX[w][lane] = xin[node * D + lane];
        }
        __syncthreads();
        if (node < n_nodes) {
            float acc = bias;
            #pragma unroll
            for (int k = 0; k < 64; ++k) {
                acc = fmaf(sA[w][k], sWr[k * 65 + lane], acc);
                acc = fmaf(sX[w][k], sWt[k * 65 + lane], acc);
            }
            float h = tanhf(acc);
            if (OUT_HEAD) {
                float v = h * wout;
                #pragma unroll
                for (int off = 32; off > 0; off >>= 1)
                    v += __shfl_down(v, off);
                if (lane == 0) out[node] = v + bout[0];
            } else {
                out[node * D + lane] = h;
            }
        }
        __syncthreads();
    }
}

// ---------------------------------------------------------------------------
extern "C" void kernel_launch(void* const* d_in, const int* in_sizes, int n_in,
                              void* d_out, int out_size, void* d_ws, size_t ws_size,
                              hipStream_t stream) {
    const float* x      = (const float*)d_in[0];
    const void*  ei     = d_in[1];
    const float* Wrel0  = (const float*)d_in[2];
    const float* brel0  = (const float*)d_in[3];
    const float* Wroot0 = (const float*)d_in[4];
    const float* Wrel1  = (const float*)d_in[5];
    const float* brel1  = (const float*)d_in[6];
    const float* Wroot1 = (const float*)d_in[7];
    const float* Wout   = (const float*)d_in[8];
    const float* bout   = (const float*)d_in[9];
    float* out = (float*)d_out;

    const int n_nodes = in_sizes[0] / D;
    const int n_edges = in_sizes[1] / 2;

    // workspace layout
    float* hbuf   = (float*)d_ws;                    // [n_nodes * 64]
    int*   rowptr = (int*)(hbuf + (size_t)n_nodes * D); // [n_nodes + 1]
    int*   deg    = rowptr + (n_nodes + 1);          // [n_nodes]
    int*   cursor = deg + n_nodes;                   // [n_nodes]
    int*   col    = cursor + n_nodes;                // [n_edges]
    int*   flag   = col + n_edges;                   // [1]

    // ---- CSR build (once; shared by both layers) ----
    detect_i64_kernel<<<1, 256, 0, stream>>>((const unsigned int*)ei, flag);
    hipMemsetAsync(deg, 0, (size_t)n_nodes * sizeof(int), stream);
    hist_kernel<<<(n_edges + 255) / 256, 256, 0, stream>>>(ei, flag, deg, n_edges);
    scan_kernel<<<1, 1024, 0, stream>>>(deg, rowptr, cursor, n_nodes);
    fill_kernel<<<(n_edges + 255) / 256, 256, 0, stream>>>(ei, flag, cursor, col, n_edges);

    // ---- layer 0: x -> hbuf ----
    layer_kernel<false><<<2048, 256, 0, stream>>>(
        x, rowptr, col, Wrel0, brel0, Wroot0, nullptr, nullptr, hbuf, n_nodes);
    // ---- layer 1 + output head: hbuf -> out ----
    layer_kernel<true><<<2048, 256, 0, stream>>>(
        hbuf, rowptr, col, Wrel1, brel1, Wroot1, Wout, bout, out, n_nodes);
}

// Round 3
// 395.045 us; speedup vs baseline: 1.5992x; 1.5545x over previous
//
#include <hip/hip_runtime.h>
#include <math.h>

#define D 64

// ---------------------------------------------------------------------------
// Detect whether edge_index buffer is int64 or int32 (values < 2^31 => if
// int64, odd 32-bit words are all zero).
__global__ void detect_i64_kernel(const unsigned int* __restrict__ ei,
                                  int* __restrict__ flag) {
    __shared__ unsigned int red[256];
    unsigned int v = 0;
    for (int i = threadIdx.x; i < 2048; i += 256)
        v |= ei[2 * i + 1];
    red[threadIdx.x] = v;
    __syncthreads();
    if (threadIdx.x == 0) {
        unsigned int o = 0;
        for (int i = 0; i < 256; ++i) o |= red[i];
        flag[0] = (o == 0) ? 1 : 0;   // 1 => int64 layout
    }
}

__device__ __forceinline__ int load_idx(const void* ei, int flag, long long pos) {
    return flag ? (int)((const long long*)ei)[pos] : ((const int*)ei)[pos];
}

// ---------------------------------------------------------------------------
// Histogram of in-degrees.
__global__ void hist_kernel(const void* __restrict__ ei,
                            const int* __restrict__ flag,
                            int* __restrict__ deg, int n_edges) {
    int e = blockIdx.x * blockDim.x + threadIdx.x;
    if (e >= n_edges) return;
    int dst = load_idx(ei, flag[0], (long long)n_edges + e);
    atomicAdd(&deg[dst], 1);
}

// ---------------------------------------------------------------------------
// Hierarchical exclusive scan (3 kernels), n up to 512*256 = 131072.
__global__ __launch_bounds__(256) void scan_block_kernel(
        const int* __restrict__ deg, int* __restrict__ rowptr,
        int* __restrict__ blocksum, int n) {
    int i = blockIdx.x * 256 + threadIdx.x;
    int v = (i < n) ? deg[i] : 0;
    int lane = threadIdx.x & 63;
    int wid = threadIdx.x >> 6;
    int s = v;
    #pragma unroll
    for (int off = 1; off < 64; off <<= 1) {
        int t = __shfl_up(s, off);
        if (lane >= off) s += t;
    }
    __shared__ int wsum[4];
    if (lane == 63) wsum[wid] = s;
    __syncthreads();
    int add = 0;
    for (int k = 0; k < wid; ++k) add += wsum[k];
    int incl = s + add;
    if (i < n) rowptr[i] = incl - v;              // local exclusive
    if (threadIdx.x == 255) blocksum[blockIdx.x] = incl;
}

__global__ __launch_bounds__(512) void scan_top_kernel(
        int* __restrict__ blocksum, int* __restrict__ rowptr_tail, int nb) {
    int t = threadIdx.x;
    int v = (t < nb) ? blocksum[t] : 0;
    int lane = t & 63;
    int wid = t >> 6;
    int s = v;
    #pragma unroll
    for (int off = 1; off < 64; off <<= 1) {
        int u = __shfl_up(s, off);
        if (lane >= off) s += u;
    }
    __shared__ int wsum[8];
    if (lane == 63) wsum[wid] = s;
    __syncthreads();
    int add = 0;
    for (int k = 0; k < wid; ++k) add += wsum[k];
    int incl = s + add;
    if (t < nb) blocksum[t] = incl - v;           // exclusive block offset
    if (t == 511) rowptr_tail[0] = incl;          // grand total (= n_edges)
}

__global__ __launch_bounds__(256) void scan_add_kernel(
        int* __restrict__ rowptr, int* __restrict__ cursor,
        const int* __restrict__ blockoff, int n) {
    int i = blockIdx.x * 256 + threadIdx.x;
    if (i < n) {
        int r = rowptr[i] + blockoff[blockIdx.x];
        rowptr[i] = r;
        cursor[i] = r;
    }
}

// ---------------------------------------------------------------------------
// Fill CSR column array: col[pos] = src, sorted by dst.
__global__ void fill_kernel(const void* __restrict__ ei,
                            const int* __restrict__ flag,
                            int* __restrict__ cursor,
                            int* __restrict__ col, int n_edges) {
    int e = blockIdx.x * blockDim.x + threadIdx.x;
    if (e >= n_edges) return;
    int f = flag[0];
    int src = load_idx(ei, f, e);
    int dst = load_idx(ei, f, (long long)n_edges + e);
    int pos = atomicAdd(&cursor[dst], 1);
    col[pos] = src;
}

// ---------------------------------------------------------------------------
// Fused GraphConv layer: per node i (one wave each, lane = feature):
//   agg = sum_{e in [rowptr[i],rowptr[i+1])} xin[col[e]]
//   h   = tanh( agg @ Wrel^T + brel + xin[i] @ Wroot^T )
// If OUT_HEAD: out[i] = dot(h, Wout) + bout   (h never hits memory)
// else:        out[i*64 + lane] = h[lane]
template <bool OUT_HEAD>
__global__ __launch_bounds__(256) void layer_kernel(
        const float* __restrict__ xin,
        const int* __restrict__ rowptr, const int* __restrict__ col,
        const float* __restrict__ Wrel, const float* __restrict__ brel,
        const float* __restrict__ Wroot,
        const float* __restrict__ Wout, const float* __restrict__ bout,
        float* __restrict__ out, int n_nodes) {
    __shared__ float sWr[64 * 65];
    __shared__ float sWt[64 * 65];
    __shared__ float sA[4][64];
    __shared__ float sX[4][64];

    int tid = threadIdx.x;
    // stage transposed weights: sW[k*65 + j] = W[j*64 + k]
    for (int idx = tid; idx < 4096; idx += 256) {
        int j = idx >> 6, k = idx & 63;
        sWr[k * 65 + j] = Wrel[idx];
        sWt[k * 65 + j] = Wroot[idx];
    }
    __syncthreads();

    int lane = tid & 63;
    int w = tid >> 6;
    float bias = brel[lane];
    float wout = OUT_HEAD ? Wout[lane] : 0.f;
    int ntiles = (n_nodes + 3) >> 2;

    for (int tile = blockIdx.x; tile < ntiles; tile += gridDim.x) {
        int node = tile * 4 + w;
        if (node < n_nodes) {
            int beg = rowptr[node];
            int end = rowptr[node + 1];
            // gather-sum with 4 independent accumulators (4 loads in flight)
            float a0 = 0.f, a1 = 0.f, a2 = 0.f, a3 = 0.f;
            int e = beg;
            for (; e + 3 < end; e += 4) {
                int s0 = col[e], s1 = col[e + 1], s2 = col[e + 2], s3 = col[e + 3];
                a0 += xin[s0 * D + lane];
                a1 += xin[s1 * D + lane];
                a2 += xin[s2 * D + lane];
                a3 += xin[s3 * D + lane];
            }
            for (; e < end; ++e) a0 += xin[col[e] * D + lane];
            sA[w][lane] = (a0 + a1) + (a2 + a3);
            sX[w][lane] = xin[node * D + lane];
        }
        __syncthreads();
        if (node < n_nodes) {
            float acc = bias;
            #pragma unroll
            for (int k = 0; k < 64; ++k) {
                acc = fmaf(sA[w][k], sWr[k * 65 + lane], acc);
                acc = fmaf(sX[w][k], sWt[k * 65 + lane], acc);
            }
            float h = tanhf(acc);
            if (OUT_HEAD) {
                float v = h * wout;
                #pragma unroll
                for (int off = 32; off > 0; off >>= 1)
                    v += __shfl_down(v, off);
                if (lane == 0) out[node] = v + bout[0];
            } else {
                out[node * D + lane] = h;
            }
        }
        __syncthreads();
    }
}

// ---------------------------------------------------------------------------
extern "C" void kernel_launch(void* const* d_in, const int* in_sizes, int n_in,
                              void* d_out, int out_size, void* d_ws, size_t ws_size,
                              hipStream_t stream) {
    const float* x      = (const float*)d_in[0];
    const void*  ei     = d_in[1];
    const float* Wrel0  = (const float*)d_in[2];
    const float* brel0  = (const float*)d_in[3];
    const float* Wroot0 = (const float*)d_in[4];
    const float* Wrel1  = (const float*)d_in[5];
    const float* brel1  = (const float*)d_in[6];
    const float* Wroot1 = (const float*)d_in[7];
    const float* Wout   = (const float*)d_in[8];
    const float* bout   = (const float*)d_in[9];
    float* out = (float*)d_out;

    const int n_nodes = in_sizes[0] / D;
    const int n_edges = in_sizes[1] / 2;
    const int nb = (n_nodes + 255) / 256;   // scan blocks (391 for 100k)

    // workspace layout
    float* hbuf     = (float*)d_ws;                       // [n_nodes * 64]
    int*   rowptr   = (int*)(hbuf + (size_t)n_nodes * D); // [n_nodes + 1]
    int*   deg      = rowptr + (n_nodes + 1);             // [n_nodes]
    int*   cursor   = deg + n_nodes;                      // [n_nodes]
    int*   blocksum = cursor + n_nodes;                   // [nb]
    int*   col      = blocksum + ((nb + 63) & ~63);       // [n_edges]
    int*   flag     = col + n_edges;                      // [1]

    // ---- CSR build (once; shared by both layers) ----
    detect_i64_kernel<<<1, 256, 0, stream>>>((const unsigned int*)ei, flag);
    hipMemsetAsync(deg, 0, (size_t)n_nodes * sizeof(int), stream);
    hist_kernel<<<(n_edges + 255) / 256, 256, 0, stream>>>(ei, flag, deg, n_edges);
    scan_block_kernel<<<nb, 256, 0, stream>>>(deg, rowptr, blocksum, n_nodes);
    scan_top_kernel<<<1, 512, 0, stream>>>(blocksum, rowptr + n_nodes, nb);
    scan_add_kernel<<<nb, 256, 0, stream>>>(rowptr, cursor, blocksum, n_nodes);
    fill_kernel<<<(n_edges + 255) / 256, 256, 0, stream>>>(ei, flag, cursor, col, n_edges);

    // ---- layer 0: x -> hbuf ----
    layer_kernel<false><<<2048, 256, 0, stream>>>(
        x, rowptr, col, Wrel0, brel0, Wroot0, nullptr, nullptr, hbuf, n_nodes);
    // ---- layer 1 + output head: hbuf -> out ----
    layer_kernel<true><<<2048, 256, 0, stream>>>(
        hbuf, rowptr, col, Wrel1, brel1, Wroot1, Wout, bout, out, n_nodes);
}

// Round 4
// 358.954 us; speedup vs baseline: 1.7600x; 1.1005x over previous
//
#include <hip/hip_runtime.h>
#include <math.h>

#define D 64

// ---------------------------------------------------------------------------
// Detect whether edge_index buffer is int64 or int32 (values < 2^31 => if
// int64, odd 32-bit words are all zero).
__global__ void detect_i64_kernel(const unsigned int* __restrict__ ei,
                                  int* __restrict__ flag) {
    __shared__ unsigned int red[256];
    unsigned int v = 0;
    for (int i = threadIdx.x; i < 2048; i += 256)
        v |= ei[2 * i + 1];
    red[threadIdx.x] = v;
    __syncthreads();
    if (threadIdx.x == 0) {
        unsigned int o = 0;
        for (int i = 0; i < 256; ++i) o |= red[i];
        flag[0] = (o == 0) ? 1 : 0;   // 1 => int64 layout
    }
}

__device__ __forceinline__ int load_idx(const void* ei, int flag, long long pos) {
    return flag ? (int)((const long long*)ei)[pos] : ((const int*)ei)[pos];
}

// ---------------------------------------------------------------------------
// Histogram of in-degrees.
__global__ void hist_kernel(const void* __restrict__ ei,
                            const int* __restrict__ flag,
                            int* __restrict__ deg, int n_edges) {
    int e = blockIdx.x * blockDim.x + threadIdx.x;
    if (e >= n_edges) return;
    int dst = load_idx(ei, flag[0], (long long)n_edges + e);
    atomicAdd(&deg[dst], 1);
}

// ---------------------------------------------------------------------------
// Hierarchical exclusive scan (3 kernels), n up to 512*256 = 131072.
__global__ __launch_bounds__(256) void scan_block_kernel(
        const int* __restrict__ deg, int* __restrict__ rowptr,
        int* __restrict__ blocksum, int n) {
    int i = blockIdx.x * 256 + threadIdx.x;
    int v = (i < n) ? deg[i] : 0;
    int lane = threadIdx.x & 63;
    int wid = threadIdx.x >> 6;
    int s = v;
    #pragma unroll
    for (int off = 1; off < 64; off <<= 1) {
        int t = __shfl_up(s, off);
        if (lane >= off) s += t;
    }
    __shared__ int wsum[4];
    if (lane == 63) wsum[wid] = s;
    __syncthreads();
    int add = 0;
    for (int k = 0; k < wid; ++k) add += wsum[k];
    int incl = s + add;
    if (i < n) rowptr[i] = incl - v;              // local exclusive
    if (threadIdx.x == 255) blocksum[blockIdx.x] = incl;
}

__global__ __launch_bounds__(512) void scan_top_kernel(
        int* __restrict__ blocksum, int* __restrict__ rowptr_tail, int nb) {
    int t = threadIdx.x;
    int v = (t < nb) ? blocksum[t] : 0;
    int lane = t & 63;
    int wid = t >> 6;
    int s = v;
    #pragma unroll
    for (int off = 1; off < 64; off <<= 1) {
        int u = __shfl_up(s, off);
        if (lane >= off) s += u;
    }
    __shared__ int wsum[8];
    if (lane == 63) wsum[wid] = s;
    __syncthreads();
    int add = 0;
    for (int k = 0; k < wid; ++k) add += wsum[k];
    int incl = s + add;
    if (t < nb) blocksum[t] = incl - v;           // exclusive block offset
    if (t == 511) rowptr_tail[0] = incl;          // grand total (= n_edges)
}

__global__ __launch_bounds__(256) void scan_add_kernel(
        int* __restrict__ rowptr, int* __restrict__ cursor,
        const int* __restrict__ blockoff, int n) {
    int i = blockIdx.x * 256 + threadIdx.x;
    if (i < n) {
        int r = rowptr[i] + blockoff[blockIdx.x];
        rowptr[i] = r;
        cursor[i] = r;
    }
}

// ---------------------------------------------------------------------------
// Fill CSR column array: col[pos] = src, sorted by dst.
__global__ void fill_kernel(const void* __restrict__ ei,
                            const int* __restrict__ flag,
                            int* __restrict__ cursor,
                            int* __restrict__ col, int n_edges) {
    int e = blockIdx.x * blockDim.x + threadIdx.x;
    if (e >= n_edges) return;
    int f = flag[0];
    int src = load_idx(ei, f, e);
    int dst = load_idx(ei, f, (long long)n_edges + e);
    int pos = atomicAdd(&cursor[dst], 1);
    col[pos] = src;
}

// ---------------------------------------------------------------------------
// Fused GraphConv layer, 512 threads = 8 waves, 4 nodes per wave.
// Gather: lane (q = lane>>4, c = lane&15): 16-lane group q walks node q's edge
//   list with float4 loads (16B/lane, 4 edges/wave-instr, unroll 4 -> 16 edges
//   in flight). acc IS the agg chunk (group == node, no cross-group reduce).
// Staging: agg/x written TRANSPOSED per wave: sAT[k*4+q] so the transform can
//   broadcast-read all 4 nodes' k-th value in one uniform float4.
// Transform: lane = output feature j. Per k: 2 conflict-free ds_read_b32
//   weight columns (stride 64: 2 lanes/bank = free) + 2 uniform float4 -> 8
//   FMAs (4 nodes). Weight LDS traffic amortized over 4 nodes.
template <bool OUT_HEAD>
__global__ __launch_bounds__(512) void layer_kernel(
        const float* __restrict__ xin,
        const int* __restrict__ rowptr, const int* __restrict__ col,
        const float* __restrict__ Wrel, const float* __restrict__ brel,
        const float* __restrict__ Wroot,
        const float* __restrict__ Wout, const float* __restrict__ bout,
        float* __restrict__ out, int n_nodes) {
    __shared__ float sWr[64 * 64];     // sWr[k*64+j] = Wrel[j][k]
    __shared__ float sWt[64 * 64];
    __shared__ float sAT[8][256];      // [wave][k*4+q]
    __shared__ float sXT[8][256];

    int tid = threadIdx.x;
    // stage transposed weights; LDS writes conflict-free (j consecutive)
    {
        int j = tid & 63;
        int ks = tid >> 6;            // 0..7
        #pragma unroll
        for (int i = 0; i < 8; ++i) {
            int k = ks + i * 8;
            sWr[k * 64 + j] = Wrel[j * 64 + k];
            sWt[k * 64 + j] = Wroot[j * 64 + k];
        }
    }
    __syncthreads();

    int w = tid >> 6;        // wave 0..7
    int lane = tid & 63;
    int q = lane >> 4;       // node sub-index 0..3
    int c = lane & 15;       // feature chunk 0..15

    int base = blockIdx.x * 32 + w * 4;
    int node = base + q;
    bool valid = node < n_nodes;
    int beg = valid ? rowptr[node] : 0;
    int end = valid ? rowptr[node + 1] : 0;

    // ---- gather (agg) ----
    float4 acc = make_float4(0.f, 0.f, 0.f, 0.f);
    for (int e = beg; __any(e < end); e += 4) {
        #pragma unroll
        for (int u = 0; u < 4; ++u) {
            if (e + u < end) {
                int s = col[e + u];
                const float4 v = *(const float4*)(xin + (size_t)s * D + c * 4);
                acc.x += v.x; acc.y += v.y; acc.z += v.z; acc.w += v.w;
            }
        }
    }
    // ---- root row ----
    float4 xv = make_float4(0.f, 0.f, 0.f, 0.f);
    if (valid) xv = *(const float4*)(xin + (size_t)node * D + c * 4);

    // ---- stage transposed (wave-private rows, no barrier needed) ----
    float* pA = &sAT[w][0];
    float* pX = &sXT[w][0];
    pA[(4 * c + 0) * 4 + q] = acc.x;
    pA[(4 * c + 1) * 4 + q] = acc.y;
    pA[(4 * c + 2) * 4 + q] = acc.z;
    pA[(4 * c + 3) * 4 + q] = acc.w;
    pX[(4 * c + 0) * 4 + q] = xv.x;
    pX[(4 * c + 1) * 4 + q] = xv.y;
    pX[(4 * c + 2) * 4 + q] = xv.z;
    pX[(4 * c + 3) * 4 + q] = xv.w;

    // ---- transform: lane = output feature j, 4 nodes at once ----
    int j = lane;
    float b = brel[j];
    float a0 = b, a1 = b, a2 = b, a3 = b;
    #pragma unroll 8
    for (int k = 0; k < 64; ++k) {
        float wr = sWr[k * 64 + j];
        float wt = sWt[k * 64 + j];
        const float4 av = *(const float4*)&pA[k * 4];   // uniform broadcast
        const float4 xk = *(const float4*)&pX[k * 4];
        a0 = fmaf(wr, av.x, a0); a0 = fmaf(wt, xk.x, a0);
        a1 = fmaf(wr, av.y, a1); a1 = fmaf(wt, xk.y, a1);
        a2 = fmaf(wr, av.z, a2); a2 = fmaf(wt, xk.z, a2);
        a3 = fmaf(wr, av.w, a3); a3 = fmaf(wt, xk.w, a3);
    }
    float h0 = tanhf(a0), h1 = tanhf(a1), h2 = tanhf(a2), h3 = tanhf(a3);

    if (OUT_HEAD) {
        float wj = Wout[j];
        float v0 = h0 * wj, v1 = h1 * wj, v2 = h2 * wj, v3 = h3 * wj;
        #pragma unroll
        for (int off = 32; off > 0; off >>= 1) {
            v0 += __shfl_xor(v0, off);
            v1 += __shfl_xor(v1, off);
            v2 += __shfl_xor(v2, off);
            v3 += __shfl_xor(v3, off);
        }
        if (lane == 0) {
            float bo = bout[0];
            if (base + 0 < n_nodes) out[base + 0] = v0 + bo;
            if (base + 1 < n_nodes) out[base + 1] = v1 + bo;
            if (base + 2 < n_nodes) out[base + 2] = v2 + bo;
            if (base + 3 < n_nodes) out[base + 3] = v3 + bo;
        }
    } else {
        if (base + 0 < n_nodes) out[(size_t)(base + 0) * D + j] = h0;
        if (base + 1 < n_nodes) out[(size_t)(base + 1) * D + j] = h1;
        if (base + 2 < n_nodes) out[(size_t)(base + 2) * D + j] = h2;
        if (base + 3 < n_nodes) out[(size_t)(base + 3) * D + j] = h3;
    }
}

// ---------------------------------------------------------------------------
extern "C" void kernel_launch(void* const* d_in, const int* in_sizes, int n_in,
                              void* d_out, int out_size, void* d_ws, size_t ws_size,
                              hipStream_t stream) {
    const float* x      = (const float*)d_in[0];
    const void*  ei     = d_in[1];
    const float* Wrel0  = (const float*)d_in[2];
    const float* brel0  = (const float*)d_in[3];
    const float* Wroot0 = (const float*)d_in[4];
    const float* Wrel1  = (const float*)d_in[5];
    const float* brel1  = (const float*)d_in[6];
    const float* Wroot1 = (const float*)d_in[7];
    const float* Wout   = (const float*)d_in[8];
    const float* bout   = (const float*)d_in[9];
    float* out = (float*)d_out;

    const int n_nodes = in_sizes[0] / D;
    const int n_edges = in_sizes[1] / 2;
    const int nb = (n_nodes + 255) / 256;   // scan blocks (391 for 100k)

    // workspace layout
    float* hbuf     = (float*)d_ws;                       // [n_nodes * 64]
    int*   rowptr   = (int*)(hbuf + (size_t)n_nodes * D); // [n_nodes + 1]
    int*   deg      = rowptr + (n_nodes + 1);             // [n_nodes]
    int*   cursor   = deg + n_nodes;                      // [n_nodes]
    int*   blocksum = cursor + n_nodes;                   // [nb]
    int*   col      = blocksum + ((nb + 63) & ~63);       // [n_edges]
    int*   flag     = col + n_edges;                      // [1]

    // ---- CSR build (once; shared by both layers) ----
    detect_i64_kernel<<<1, 256, 0, stream>>>((const unsigned int*)ei, flag);
    hipMemsetAsync(deg, 0, (size_t)n_nodes * sizeof(int), stream);
    hist_kernel<<<(n_edges + 255) / 256, 256, 0, stream>>>(ei, flag, deg, n_edges);
    scan_block_kernel<<<nb, 256, 0, stream>>>(deg, rowptr, blocksum, n_nodes);
    scan_top_kernel<<<1, 512, 0, stream>>>(blocksum, rowptr + n_nodes, nb);
    scan_add_kernel<<<nb, 256, 0, stream>>>(rowptr, cursor, blocksum, n_nodes);
    fill_kernel<<<(n_edges + 255) / 256, 256, 0, stream>>>(ei, flag, cursor, col, n_edges);

    const int nlb = (n_nodes + 31) / 32;   // 3125 for 100k
    // ---- layer 0: x -> hbuf ----
    layer_kernel<false><<<nlb, 512, 0, stream>>>(
        x, rowptr, col, Wrel0, brel0, Wroot0, nullptr, nullptr, hbuf, n_nodes);
    // ---- layer 1 + output head: hbuf -> out ----
    layer_kernel<true><<<nlb, 512, 0, stream>>>(
        hbuf, rowptr, col, Wrel1, brel1, Wroot1, Wout, bout, out, n_nodes);
}